// Round 5
// baseline (127.153 us; speedup 1.0000x reference)
//
#include <hip/hip_runtime.h>

// AnalyticalBoundedLineAttractor — exact linear-regime stepping via Taylor
// recurrence:
//   z = Wx + b; m_dt = (z>0)?dt:0
//   w1 = m_dt*z - dt*x;  wk = (m_dt*(W w) - dt*w)/k;  x+ = x + sum wk
// K=3 terms; measured absmax 0.0156 vs threshold 7.7e-2.
//
// R4 post-mortem: VGPR_Count=48 with a 64-float row array => the compiler
// was NOT keeping W register-resident; it refetched W per matvec (L1/L2-hot,
// so invisible in FETCH_SIZE). Fixes:
//  (a) amdgpu_waves_per_eu(1,1) — occupancy target 1 wave/EU, 512-VGPR
//      budget, removes the pressure heuristic that caused the remat — plus
//      per-element asm "+v" pins making Wr non-rematerializable.
//  (b) dual-pipe broadcast: j=0..31 via v_readlane+v_fmac (VALU pipe),
//      j=32..63 via ds_write_b32 + 8 broadcast ds_read_b128 (LDS pipe,
//      single wave: no barrier; double-buffered across matvecs) consumed
//      with v_pk_fma_f32 (float2 elementwise fma). LDS first-return
//      latency hides under the readlane half.

#define DT_F 0.05f
#define T_STEPS 100
#define DD 64
#define KT 3  // Taylor terms w_1..w_KT

typedef float v2f __attribute__((ext_vector_type(2)));

__device__ __forceinline__ float matvec64(const float (&Wr)[DD], float w,
                                          float* __restrict__ sb, int lane) {
    // LDS pipe: stage w, issue all broadcast reads for j=32..63 up front.
    // Single wave: DS ops execute in order, no barrier needed.
    sb[lane] = w;
    float4 q0 = *reinterpret_cast<const float4*>(sb + 32);
    float4 q1 = *reinterpret_cast<const float4*>(sb + 36);
    float4 q2 = *reinterpret_cast<const float4*>(sb + 40);
    float4 q3 = *reinterpret_cast<const float4*>(sb + 44);
    float4 q4 = *reinterpret_cast<const float4*>(sb + 48);
    float4 q5 = *reinterpret_cast<const float4*>(sb + 52);
    float4 q6 = *reinterpret_cast<const float4*>(sb + 56);
    float4 q7 = *reinterpret_cast<const float4*>(sb + 60);

    // VALU pipe meanwhile: j=0..31 via readlane broadcast.
    const int wi = __float_as_int(w);
    float a0 = 0.f, a1 = 0.f, a2 = 0.f, a3 = 0.f;
#pragma unroll
    for (int j = 0; j < 32; j += 4) {
        const float s0 = __int_as_float(__builtin_amdgcn_readlane(wi, j + 0));
        const float s1 = __int_as_float(__builtin_amdgcn_readlane(wi, j + 1));
        const float s2 = __int_as_float(__builtin_amdgcn_readlane(wi, j + 2));
        const float s3 = __int_as_float(__builtin_amdgcn_readlane(wi, j + 3));
        a0 = fmaf(Wr[j + 0], s0, a0);
        a1 = fmaf(Wr[j + 1], s1, a1);
        a2 = fmaf(Wr[j + 2], s2, a2);
        a3 = fmaf(Wr[j + 3], s3, a3);
    }

    // Consume the LDS half with packed-f32 FMAs (v_pk_fma_f32).
    v2f p0 = {0.f, 0.f}, p1 = {0.f, 0.f};
#pragma unroll
    for (int r = 0; r < 8; ++r) {
        const float4 q = (r == 0) ? q0 : (r == 1) ? q1 : (r == 2) ? q2 :
                         (r == 3) ? q3 : (r == 4) ? q4 : (r == 5) ? q5 :
                         (r == 6) ? q6 : q7;
        const int j = 32 + 4 * r;
        v2f wa = {Wr[j + 0], Wr[j + 1]};
        v2f wb = {Wr[j + 2], Wr[j + 3]};
        v2f sa = {q.x, q.y};
        v2f sc = {q.z, q.w};
        p0 = __builtin_elementwise_fma(wa, sa, p0);
        p1 = __builtin_elementwise_fma(wb, sc, p1);
    }
    const v2f ps = p0 + p1;
    return (((a0 + a1) + (a2 + a3)) + (ps.x + ps.y));
}

__global__ __launch_bounds__(64, 1)
__attribute__((amdgpu_waves_per_eu(1, 1)))
void abla_kernel(const float* __restrict__ x0,
                 const float* __restrict__ W,
                 const float* __restrict__ bvec,
                 float* __restrict__ out) {
    const int batch = blockIdx.x;
    const int lane = threadIdx.x;

    __shared__ float sbuf[2][DD];  // broadcast double buffer (512 B)

    // Lane i caches row i of W in 64 VGPRs — one-time load, then pin each
    // element in a VGPR so the compiler cannot remat/refetch it per matvec
    // (R3/R4 did exactly that: VGPR_Count=48 < 64).
    float Wr[DD];
#pragma unroll
    for (int j = 0; j < DD; j += 4) {
        const float4 w4 = *reinterpret_cast<const float4*>(W + lane * DD + j);
        Wr[j + 0] = w4.x; Wr[j + 1] = w4.y; Wr[j + 2] = w4.z; Wr[j + 3] = w4.w;
    }
#pragma unroll
    for (int j = 0; j < DD; ++j)
        asm("" : "+v"(Wr[j]));

    const float bi = bvec[lane];
    float x = x0[batch * DD + lane];
    float* outp = out + (size_t)batch * T_STEPS * DD + lane;

    float* sA = &sbuf[0][0];
    float* sB = &sbuf[1][0];

    for (int t = 0; t < T_STEPS; ++t) {
        // Trajectory stores the state BEFORE the update (off critical path).
        outp[(size_t)t * DD] = x;

        // term 1: z = Wx + b gives the regime mask
        const float z = matvec64(Wr, x, sA, lane) + bi;
        const float m_dt = (z > 0.f) ? DT_F : 0.f;
        float w = m_dt * z - DT_F * x;
        float y = x + w;

        // term 2
        {
            const float v = matvec64(Wr, w, sB, lane);
            w = (m_dt * v - DT_F * w) * 0.5f;
            y += w;
        }
        // term 3
        {
            const float v = matvec64(Wr, w, sA, lane);
            w = (m_dt * v - DT_F * w) * (1.0f / 3.0f);
            y += w;
        }
        x = y;
        // Swap buffers so consecutive matvecs never reuse the same slot
        // back-to-back (step pattern A,B,A | B,A,B | ...).
        float* tmp = sA; sA = sB; sB = tmp;
    }
}

extern "C" void kernel_launch(void* const* d_in, const int* in_sizes, int n_in,
                              void* d_out, int out_size, void* d_ws, size_t ws_size,
                              hipStream_t stream) {
    const float* x0 = (const float*)d_in[0];   // (256, 64) f32
    const float* W  = (const float*)d_in[1];   // (64, 64)  f32
    const float* b  = (const float*)d_in[2];   // (64,)     f32
    float* out = (float*)d_out;                // (256, 100, 64) f32

    const int batch = in_sizes[0] / DD;        // 256
    abla_kernel<<<batch, DD, 0, stream>>>(x0, W, b, out);
}